// Round 1
// baseline (416.750 us; speedup 1.0000x reference)
//
#include <hip/hip_runtime.h>
#include <hip/hip_bf16.h>

// GRU: B=4096, T=120, I=64, H=128. Gate order r,z,n (PyTorch).
// One block = 16 batch rows, 512 threads = 8 waves, persistent over all T.
// Wave w computes gate columns [16w,16w+16) of r, z, n via 16x16x32 bf16 MFMA
// (gate-aligned tiles -> nonlinearity fully in registers).
// Weights live in VGPRs for the whole kernel; h carried in fp32 registers,
// bf16 copy round-trips LDS only for the next step's A-operand.

#define Bv 4096
#define Tv 120
#define Iv 64
#define Hv 128

typedef __attribute__((ext_vector_type(8))) short short8;
typedef __attribute__((ext_vector_type(4))) float floatx4;

#if __has_builtin(__builtin_amdgcn_exp2f)
#define EXP2F(x) __builtin_amdgcn_exp2f(x)
#else
#define EXP2F(x) exp2f(x)
#endif
#if __has_builtin(__builtin_amdgcn_rcpf)
#define RCPF(x) __builtin_amdgcn_rcpf(x)
#else
#define RCPF(x) (1.0f / (x))
#endif

__device__ inline short f2bf(float f) {
    union { float f; unsigned u; } v; v.f = f;
    unsigned r = v.u + 0x7FFFu + ((v.u >> 16) & 1u);  // RNE
    return (short)(r >> 16);
}

__device__ inline float sigmoid_fast(float x) {
    // 1/(1+exp(-x)) = 1/(1+2^(-x*log2e))
    return RCPF(1.0f + EXP2F(-1.44269504f * x));
}
__device__ inline float tanh_fast(float x) {
    // 1 - 2/(1+exp(2x)); stable at both infinities
    return 1.0f - 2.0f * RCPF(1.0f + EXP2F(2.88539008f * x));
}

__launch_bounds__(512, 2)
__global__ void gru_persist(const float* __restrict__ x,
                            const float* __restrict__ W_ih,
                            const float* __restrict__ W_hh,
                            const float* __restrict__ b_ih,
                            const float* __restrict__ b_hh,
                            float* __restrict__ out) {
    constexpr int XSTR = 72;   // bf16 elems/row for x tile (16B-aligned, 2-way-free banks)
    constexpr int HSTR = 136;  // bf16 elems/row for h tile
    __shared__ short h_lds[16 * HSTR];
    __shared__ short x_lds[2][16 * XSTR];

    const int tid  = threadIdx.x;
    const int wave = tid >> 6;       // 0..7
    const int lane = tid & 63;
    const int s    = lane & 15;      // col within 16-tile / A row
    const int quad = lane >> 4;      // 0..3
    const int b0   = blockIdx.x * 16;
    const int c    = wave * 16 + s;  // gate column within [0,128)

    // ---- biases (r/z can pre-sum ih+hh; n must keep them split) ----
    const float bias_r  = b_ih[c] + b_hh[c];
    const float bias_z  = b_ih[c + 128] + b_hh[c + 128];
    const float bias_xn = b_ih[c + 256];
    const float bias_hn = b_hh[c + 256];

    // ---- preload weight B-fragments into registers (persist all T) ----
    // B-frag: lane holds W[n_abs][k], k = kst*32 + quad*8 + j
    short8 whh[3][4];
    short8 wih[3][2];
#pragma unroll
    for (int g = 0; g < 3; ++g) {
        const float* wr = W_hh + (size_t)(g * 128 + c) * 128;
#pragma unroll
        for (int kst = 0; kst < 4; ++kst) {
            const float* p = wr + kst * 32 + quad * 8;
            floatx4 lo = *(const floatx4*)p;
            floatx4 hi = *(const floatx4*)(p + 4);
            short8 f;
            f[0] = f2bf(lo[0]); f[1] = f2bf(lo[1]); f[2] = f2bf(lo[2]); f[3] = f2bf(lo[3]);
            f[4] = f2bf(hi[0]); f[5] = f2bf(hi[1]); f[6] = f2bf(hi[2]); f[7] = f2bf(hi[3]);
            whh[g][kst] = f;
        }
        const float* wi = W_ih + (size_t)(g * 128 + c) * 64;
#pragma unroll
        for (int kst = 0; kst < 2; ++kst) {
            const float* p = wi + kst * 32 + quad * 8;
            floatx4 lo = *(const floatx4*)p;
            floatx4 hi = *(const floatx4*)(p + 4);
            short8 f;
            f[0] = f2bf(lo[0]); f[1] = f2bf(lo[1]); f[2] = f2bf(lo[2]); f[3] = f2bf(lo[3]);
            f[4] = f2bf(hi[0]); f[5] = f2bf(hi[1]); f[6] = f2bf(hi[2]); f[7] = f2bf(hi[3]);
            wih[g][kst] = f;
        }
    }

    // ---- zero h_lds, fp32 h carry; stage x[t=0] ----
    for (int i = tid; i < 16 * HSTR; i += 512) h_lds[i] = 0;
    float hcar[4] = {0.f, 0.f, 0.f, 0.f};

    const int xrow = tid >> 5, xcp = tid & 31;   // 16 rows x 32 float2
    const float* xbase = x + ((size_t)(b0 + xrow) * Tv) * Iv + xcp * 2;
    {
        float2 v = *(const float2*)xbase;
        unsigned pk = (unsigned short)f2bf(v.x) | ((unsigned)(unsigned short)f2bf(v.y) << 16);
        *(unsigned*)&x_lds[0][xrow * XSTR + xcp * 2] = pk;
    }
    __syncthreads();

    float* hT = out + (size_t)Bv * Tv * Hv;
    // per-lane output base: row = quad*4 + r, col = c
    const size_t obase = ((size_t)(b0 + quad * 4) * Tv) * Hv + c;

#pragma unroll 1
    for (int t = 0; t < Tv; ++t) {
        // prefetch next x tile (global -> regs), hides HBM latency behind compute
        float2 xv;
        if (t + 1 < Tv) xv = *(const float2*)(xbase + (size_t)(t + 1) * Iv);

        // A-fragments: shared h tile + staged x tile
        const short* hrow = &h_lds[s * HSTR];
        short8 ah0 = *(const short8*)(hrow + quad * 8);
        short8 ah1 = *(const short8*)(hrow + 32 + quad * 8);
        short8 ah2 = *(const short8*)(hrow + 64 + quad * 8);
        short8 ah3 = *(const short8*)(hrow + 96 + quad * 8);
        const short* xr = &x_lds[t & 1][s * XSTR];
        short8 ax0 = *(const short8*)(xr + quad * 8);
        short8 ax1 = *(const short8*)(xr + 32 + quad * 8);

        floatx4 accr  = {bias_r, bias_r, bias_r, bias_r};
        floatx4 accz  = {bias_z, bias_z, bias_z, bias_z};
        floatx4 accxn = {bias_xn, bias_xn, bias_xn, bias_xn};
        floatx4 acchn = {bias_hn, bias_hn, bias_hn, bias_hn};

        accr  = __builtin_amdgcn_mfma_f32_16x16x32_bf16(ah0, whh[0][0], accr, 0, 0, 0);
        accz  = __builtin_amdgcn_mfma_f32_16x16x32_bf16(ah0, whh[1][0], accz, 0, 0, 0);
        acchn = __builtin_amdgcn_mfma_f32_16x16x32_bf16(ah0, whh[2][0], acchn, 0, 0, 0);
        accr  = __builtin_amdgcn_mfma_f32_16x16x32_bf16(ah1, whh[0][1], accr, 0, 0, 0);
        accz  = __builtin_amdgcn_mfma_f32_16x16x32_bf16(ah1, whh[1][1], accz, 0, 0, 0);
        acchn = __builtin_amdgcn_mfma_f32_16x16x32_bf16(ah1, whh[2][1], acchn, 0, 0, 0);
        accr  = __builtin_amdgcn_mfma_f32_16x16x32_bf16(ah2, whh[0][2], accr, 0, 0, 0);
        accz  = __builtin_amdgcn_mfma_f32_16x16x32_bf16(ah2, whh[1][2], accz, 0, 0, 0);
        acchn = __builtin_amdgcn_mfma_f32_16x16x32_bf16(ah2, whh[2][2], acchn, 0, 0, 0);
        accr  = __builtin_amdgcn_mfma_f32_16x16x32_bf16(ah3, whh[0][3], accr, 0, 0, 0);
        accz  = __builtin_amdgcn_mfma_f32_16x16x32_bf16(ah3, whh[1][3], accz, 0, 0, 0);
        acchn = __builtin_amdgcn_mfma_f32_16x16x32_bf16(ah3, whh[2][3], acchn, 0, 0, 0);

        accr  = __builtin_amdgcn_mfma_f32_16x16x32_bf16(ax0, wih[0][0], accr, 0, 0, 0);
        accz  = __builtin_amdgcn_mfma_f32_16x16x32_bf16(ax0, wih[1][0], accz, 0, 0, 0);
        accxn = __builtin_amdgcn_mfma_f32_16x16x32_bf16(ax0, wih[2][0], accxn, 0, 0, 0);
        accr  = __builtin_amdgcn_mfma_f32_16x16x32_bf16(ax1, wih[0][1], accr, 0, 0, 0);
        accz  = __builtin_amdgcn_mfma_f32_16x16x32_bf16(ax1, wih[1][1], accz, 0, 0, 0);
        accxn = __builtin_amdgcn_mfma_f32_16x16x32_bf16(ax1, wih[2][1], accxn, 0, 0, 0);

        __syncthreads();  // all A-frag reads drained; safe to overwrite h_lds

        // gate math fully in registers: lane owns (rows quad*4+r, col c)
#pragma unroll
        for (int r = 0; r < 4; ++r) {
            float rg = sigmoid_fast(accr[r]);
            float zg = sigmoid_fast(accz[r]);
            float ng = tanh_fast(accxn[r] + rg * acchn[r]);
            float h  = (1.0f - zg) * ng + zg * hcar[r];
            hcar[r] = h;
            out[obase + (size_t)r * Tv * Hv + (size_t)t * Hv] = h;
            h_lds[(quad * 4 + r) * HSTR + c] = f2bf(h);
            if (t == Tv - 1) hT[(size_t)(b0 + quad * 4 + r) * Hv + c] = h;
        }

        // stage prefetched x for t+1
        if (t + 1 < Tv) {
            unsigned pk = (unsigned short)f2bf(xv.x) | ((unsigned)(unsigned short)f2bf(xv.y) << 16);
            *(unsigned*)&x_lds[(t + 1) & 1][xrow * XSTR + xcp * 2] = pk;
        }
        __syncthreads();  // h_lds / x_lds ready for next step
    }
}

extern "C" void kernel_launch(void* const* d_in, const int* in_sizes, int n_in,
                              void* d_out, int out_size, void* d_ws, size_t ws_size,
                              hipStream_t stream) {
    (void)in_sizes; (void)n_in; (void)out_size; (void)d_ws; (void)ws_size;
    const float* x    = (const float*)d_in[0];
    const float* W_ih = (const float*)d_in[1];
    const float* W_hh = (const float*)d_in[2];
    const float* b_ih = (const float*)d_in[3];
    const float* b_hh = (const float*)d_in[4];
    float* out = (float*)d_out;
    hipLaunchKernelGGL(gru_persist, dim3(Bv / 16), dim3(512), 0, stream,
                       x, W_ih, W_hh, b_ih, b_hh, out);
}